// Round 13
// baseline (70.860 us; speedup 1.0000x reference)
//
#include <hip/hip_runtime.h>
#include <hip/hip_bf16.h>
#include <math.h>

#define NB 256
#define NL 256
#define NH 128
#define NK 8

typedef __attribute__((ext_vector_type(8))) short bf16x8;
typedef __attribute__((ext_vector_type(4))) short s16x4;
typedef __attribute__((ext_vector_type(4))) float f32x4;

static __device__ __forceinline__ short f2bf(float x) {
    __hip_bfloat16 b = __float2bfloat16(x);
    return *reinterpret_cast<short*>(&b);
}
static __device__ __forceinline__ float bf2f(short s) {
    union { unsigned int u; float f; } v;
    v.u = ((unsigned int)(unsigned short)s) << 16;
    return v.f;
}

#define MFMA __builtin_amdgcn_mfma_f32_16x16x32_bf16

// ---------------------------------------------------------------------------
// Setup: split W into bf16 hi/lo (row-major only; transposes no longer needed).
// ---------------------------------------------------------------------------
__global__ __launch_bounds__(256) void setup_w_kernel(const float* __restrict__ W,
                                                      short* __restrict__ whi,
                                                      short* __restrict__ wlo) {
    const int id = blockIdx.x * 256 + threadIdx.x;   // h*128 + j
    const float w = W[id];
    const short hi = f2bf(w);
    whi[id] = hi;
    wlo[id] = f2bf(w - bf2f(hi));
}

// ---------------------------------------------------------------------------
// Fused per-batch kernel: 256 blocks x 1024 threads (16 waves).
// hat^T staged in LDS via MFMA; iteration = {P1 exp | P2' cap | P6' delta}.
// W out of the loop. eT restaged at end for mu only.
// ---------------------------------------------------------------------------
__global__ __launch_bounds__(1024) void fused_kernel(const float* __restrict__ e,
                                                     const float* __restrict__ b_init,
                                                     const short* __restrict__ whi,
                                                     const short* __restrict__ wlo,
                                                     float* __restrict__ out) {
    const int b = blockIdx.x;
    const int t = threadIdx.x;
    const int lane = t & 63, wv = t >> 6;
    const int l16 = lane & 15, grp = lane >> 4;

    __shared__ __align__(16) short tThi[128 * 264]; // 67584 B  hat^T hi, later e^T hi
    __shared__ __align__(16) short tTlo[128 * 264]; // 67584 B  hat^T lo, later e^T lo
    __shared__ __align__(16) short cax[16 * 264];   // 8448 B   raw exp rows 0-7 hi, 8-15 lo
    __shared__ __align__(16) short mpk[16 * 136];   // 4352 B   m_raw hi/lo (end only)
    __shared__ __align__(16) short cappk[16 * 136]; // 4352 B   cap (ksum-scaled) hi/lo
    __shared__ __align__(16) short gpk[16 * 136];   // 4352 B   mu hi/lo (end only)
    __shared__ float enl[256];                      // 1024 B
    __shared__ float red32[128];                    // 512 B
    __shared__ __align__(16) float nrmp[64];        // 256 B
    __shared__ float ksf[8], svals[8], strv[8], Ps[28];

    const float* ebg = e + (size_t)b * (NL * NH);

    // ---- per-lane e row-fragments + row norms ----
    bf16x8 eah[4], eal[4];
    {
        const int row = wv * 16 + l16;
        float ss = 0.f;
#pragma unroll
        for (int ks = 0; ks < 4; ++ks) {
            const float4 f0 = *(const float4*)&ebg[row * 128 + ks * 32 + grp * 8];
            const float4 f1 = *(const float4*)&ebg[row * 128 + ks * 32 + grp * 8 + 4];
            const float fx[8] = {f0.x, f0.y, f0.z, f0.w, f1.x, f1.y, f1.z, f1.w};
            bf16x8 hv, lv;
#pragma unroll
            for (int j = 0; j < 8; ++j) {
                const short h = f2bf(fx[j]);
                hv[j] = h;
                lv[j] = f2bf(fx[j] - bf2f(h));
                ss += fx[j] * fx[j];
            }
            eah[ks] = hv;
            eal[ks] = lv;
        }
        ss += __shfl_xor(ss, 16);
        ss += __shfl_xor(ss, 32);
        if (grp == 0) enl[row] = sqrtf(ss) + 1e-8f;
    }

    // ---- stage hat^T = W @ e^T via MFMA: wave wv owns l-cols wv*16..+16 ----
    // D[h-tile][l]: A = W rows (global hi/lo), B = e-row frags (regs).
    {
#pragma unroll
        for (int ht = 0; ht < 8; ++ht) {
            const int h0 = ht * 16;
            f32x4 a0 = (f32x4){0.f, 0.f, 0.f, 0.f};
            f32x4 a1 = (f32x4){0.f, 0.f, 0.f, 0.f};
#pragma unroll
            for (int ks = 0; ks < 4; ++ks) {
                const int ao = (h0 + l16) * 128 + ks * 32 + grp * 8;
                const bf16x8 awh = *(const bf16x8*)&whi[ao];
                const bf16x8 awl = *(const bf16x8*)&wlo[ao];
                a0 = MFMA(awh, eah[ks], a0, 0, 0, 0);
                a0 = MFMA(awh, eal[ks], a0, 0, 0, 0);
                a1 = MFMA(awl, eah[ks], a1, 0, 0, 0);
            }
#pragma unroll
            for (int r = 0; r < 4; ++r) {
                const float v = a0[r] + a1[r];
                const short hv = f2bf(v);
                const int o = (h0 + grp * 4 + r) * 264 + wv * 16 + l16;
                tThi[o] = hv;
                tTlo[o] = f2bf(v - bf2f(hv));
            }
        }
    }

    // ---- logits in registers: lane l16<8 = capsule k, l = wv*16+grp*4+r ----
    float lr0 = 0.f, lr1 = 0.f, lr2 = 0.f, lr3 = 0.f;
    if (l16 < 8) {
        const float4 bi = *(const float4*)&b_init[(size_t)b * 2048 + l16 * 256 + wv * 16 + grp * 4];
        lr0 = bi.x; lr1 = bi.y; lr2 = bi.z; lr3 = bi.w;
    }
    __syncthreads();   // B0: hat^T ready

    // ---- read back hat row-fragments (lane's row = wv*16+l16) ----
    bf16x8 hah[4], hal[4];
#pragma unroll
    for (int ks = 0; ks < 4; ++ks) {
#pragma unroll
        for (int j = 0; j < 8; ++j) {
            const int o = (ks * 32 + grp * 8 + j) * 264 + wv * 16 + l16;
            hah[ks][j] = tThi[o];
            hal[ks][j] = tTlo[o];
        }
    }

    for (int iter = 0; iter < 3; ++iter) {
        // ===== P1: raw exp (no norm, no max-sub; f32-safe) =====
        {
            const float e0 = expf(lr0), e1 = expf(lr1);
            const float e2 = expf(lr2), e3 = expf(lr3);
            float s4 = e0 + e1 + e2 + e3;
            s4 += __shfl_xor(s4, 16);
            s4 += __shfl_xor(s4, 32);
            if (l16 < 8 && grp == 0) red32[wv * 8 + l16] = s4;
            if (l16 < 8) {
                const int lb = wv * 16 + grp * 4;
                const float cv[4] = {e0, e1, e2, e3};
                s16x4 his, los;
#pragma unroll
                for (int j = 0; j < 4; ++j) {
                    const short h = f2bf(cv[j]);
                    his[j] = h;
                    los[j] = f2bf(cv[j] - bf2f(h));
                }
                *(s16x4*)&cax[l16 * 264 + lb] = his;
                *(s16x4*)&cax[(l16 + 8) * 264 + lb] = los;
            }
        }
        __syncthreads();   // B1

        // ===== P2': cap = (exp @ hat^T) * (1/ksum) + norm partials =====
        if (wv < 8) {
            float inv = 0.f;
            if (l16 < 8) {
                float kss = 0.f;
#pragma unroll
                for (int w = 0; w < 16; ++w) kss += red32[w * 8 + l16];
                inv = 1.0f / kss;
            }
            const int n0 = wv * 16;
            f32x4 ac0 = (f32x4){0.f, 0.f, 0.f, 0.f};
            f32x4 ac1 = (f32x4){0.f, 0.f, 0.f, 0.f};
#pragma unroll
            for (int ks = 0; ks < 4; ++ks) {
                const bf16x8 af = *(const bf16x8*)&cax[l16 * 264 + ks * 32 + grp * 8];
                const bf16x8 bh = *(const bf16x8*)&tThi[(n0 + l16) * 264 + ks * 32 + grp * 8];
                const bf16x8 bl = *(const bf16x8*)&tTlo[(n0 + l16) * 264 + ks * 32 + grp * 8];
                ac0 = MFMA(af, bh, ac0, 0, 0, 0);
                ac0 = MFMA(af, bl, ac0, 0, 0, 0);
            }
#pragma unroll
            for (int ks = 4; ks < 8; ++ks) {
                const bf16x8 af = *(const bf16x8*)&cax[l16 * 264 + ks * 32 + grp * 8];
                const bf16x8 bh = *(const bf16x8*)&tThi[(n0 + l16) * 264 + ks * 32 + grp * 8];
                const bf16x8 bl = *(const bf16x8*)&tTlo[(n0 + l16) * 264 + ks * 32 + grp * 8];
                ac1 = MFMA(af, bh, ac1, 0, 0, 0);
                ac1 = MFMA(af, bl, ac1, 0, 0, 0);
            }
            const f32x4 acc = ac0 + ac1;
            f32x4 cs;
            float pn[4];
#pragma unroll
            for (int r = 0; r < 4; ++r) {
                cs[r] = acc[r] + __shfl_xor(acc[r], 32);
                cs[r] *= __shfl(inv, grp * 4 + r);
                float p2 = cs[r] * cs[r];
                p2 += __shfl_xor(p2, 1);
                p2 += __shfl_xor(p2, 2);
                p2 += __shfl_xor(p2, 4);
                p2 += __shfl_xor(p2, 8);
                pn[r] = p2;
            }
            if (l16 == 0 && grp < 2) {
                float4 pv;
                pv.x = pn[0]; pv.y = pn[1]; pv.z = pn[2]; pv.w = pn[3];
                *(float4*)&nrmp[wv * 8 + grp * 4] = pv;
            }
            if (iter < 2 && grp < 2) {
#pragma unroll
                for (int r = 0; r < 4; ++r) {
                    const int k = grp * 4 + r, h = n0 + l16;
                    const short hv = f2bf(cs[r]);
                    cappk[k * 136 + h] = hv;
                    cappk[(k + 8) * 136 + h] = f2bf(cs[r] - bf2f(hv));
                }
            }
            if (iter == 2 && wv == 0 && grp == 0 && l16 < 8) ksf[l16] = inv;
        }
        __syncthreads();   // B2

        if (iter < 2) {
            // ===== P6': logits += squash_sc * (hat_rows . cap) =====
            float sc;
            {
                float n = 0.f;
#pragma unroll
                for (int w = 0; w < 8; ++w) n += nrmp[w * 8 + (l16 & 7)];
                sc = n / (1.0f + n) / sqrtf(n + 1e-9f);
            }
            f32x4 acc = (f32x4){0.f, 0.f, 0.f, 0.f};
#pragma unroll
            for (int ks = 0; ks < 4; ++ks) {
                const bf16x8 bf = *(const bf16x8*)&cappk[l16 * 136 + ks * 32 + grp * 8];
                acc = MFMA(hah[ks], bf, acc, 0, 0, 0);
                acc = MFMA(hal[ks], bf, acc, 0, 0, 0);
            }
            lr0 += sc * (acc[0] + __shfl_xor(acc[0], 8));
            lr1 += sc * (acc[1] + __shfl_xor(acc[1], 8));
            lr2 += sc * (acc[2] + __shfl_xor(acc[2], 8));
            lr3 += sc * (acc[3] + __shfl_xor(acc[3], 8));
            // no trailing barrier (next P1 touches disjoint state)
        }
    }

    // ===== restage e^T into tT (hat^T dead) ∥ strength from nrmp =====
    if (wv == 8 && lane < 8) {
        float n = 0.f;
#pragma unroll
        for (int w = 0; w < 8; ++w) n += nrmp[w * 8 + lane];
        strv[lane] = n / (1.0f + n) * sqrtf(n) / sqrtf(n + 1e-9f);
    }
#pragma unroll
    for (int i = 0; i < 4; ++i) {
        const int p = i * 1024 + t;
        const int h = p & 127, c = p >> 7;
        float le[8];
#pragma unroll
        for (int j = 0; j < 8; ++j) le[j] = ebg[(c * 8 + j) * 128 + h];
        bf16x8 hv, lv;
#pragma unroll
        for (int j = 0; j < 8; ++j) {
            const short s = f2bf(le[j]);
            hv[j] = s;
            lv[j] = f2bf(le[j] - bf2f(s));
        }
        *(bf16x8*)&tThi[h * 264 + c * 8] = hv;
        *(bf16x8*)&tTlo[h * 264 + c * 8] = lv;
    }
    __syncthreads();   // B3

    // ===== m_raw = exp_final @ e (MFMA over restaged e^T) =====
    if (wv < 8) {
        const int n0 = wv * 16;
        f32x4 ac0 = (f32x4){0.f, 0.f, 0.f, 0.f};
        f32x4 ac1 = (f32x4){0.f, 0.f, 0.f, 0.f};
#pragma unroll
        for (int ks = 0; ks < 4; ++ks) {
            const bf16x8 af = *(const bf16x8*)&cax[l16 * 264 + ks * 32 + grp * 8];
            const bf16x8 bh = *(const bf16x8*)&tThi[(n0 + l16) * 264 + ks * 32 + grp * 8];
            const bf16x8 bl = *(const bf16x8*)&tTlo[(n0 + l16) * 264 + ks * 32 + grp * 8];
            ac0 = MFMA(af, bh, ac0, 0, 0, 0);
            ac0 = MFMA(af, bl, ac0, 0, 0, 0);
        }
#pragma unroll
        for (int ks = 4; ks < 8; ++ks) {
            const bf16x8 af = *(const bf16x8*)&cax[l16 * 264 + ks * 32 + grp * 8];
            const bf16x8 bh = *(const bf16x8*)&tThi[(n0 + l16) * 264 + ks * 32 + grp * 8];
            const bf16x8 bl = *(const bf16x8*)&tTlo[(n0 + l16) * 264 + ks * 32 + grp * 8];
            ac1 = MFMA(af, bh, ac1, 0, 0, 0);
            ac1 = MFMA(af, bl, ac1, 0, 0, 0);
        }
        const f32x4 acc = ac0 + ac1;
        f32x4 ms;
#pragma unroll
        for (int r = 0; r < 4; ++r) ms[r] = acc[r] + __shfl_xor(acc[r], 32);
        if (grp < 2) {
#pragma unroll
            for (int r = 0; r < 4; ++r) {
                const int k = grp * 4 + r, h = n0 + l16;
                const short hv = f2bf(ms[r]);
                mpk[k * 136 + h] = hv;
                mpk[(k + 8) * 136 + h] = f2bf(ms[r] - bf2f(hv));
            }
        }
    }
    __syncthreads();   // B4

    // ===== mu_n = m / (||m|| + 1e-8) -> gpk (waves 0-7) =====
    if (wv < 8) {
        const int k = wv;
        float x0 = bf2f(mpk[k * 136 + lane]) + bf2f(mpk[(k + 8) * 136 + lane]);
        float x1 = bf2f(mpk[k * 136 + 64 + lane]) + bf2f(mpk[(k + 8) * 136 + 64 + lane]);
        float s = x0 * x0 + x1 * x1;
#pragma unroll
        for (int o = 32; o; o >>= 1) s += __shfl_xor(s, o);
        const float nv = sqrtf(s) + 1e-8f;
        x0 /= nv; x1 /= nv;
        short hv = f2bf(x0);
        gpk[k * 136 + lane] = hv;
        gpk[(k + 8) * 136 + lane] = f2bf(x0 - bf2f(hv));
        hv = f2bf(x1);
        gpk[k * 136 + 64 + lane] = hv;
        gpk[(k + 8) * 136 + 64 + lane] = f2bf(x1 - bf2f(hv));
    }
    __syncthreads();   // B5

    // ===== P9: dot = e . mu (A=e regs), weight by c/enl ∥ Gram pairs =====
    {
        f32x4 acc = (f32x4){0.f, 0.f, 0.f, 0.f};
#pragma unroll
        for (int ks = 0; ks < 4; ++ks) {
            const bf16x8 bf = *(const bf16x8*)&gpk[l16 * 136 + ks * 32 + grp * 8];
            acc = MFMA(eah[ks], bf, acc, 0, 0, 0);
            acc = MFMA(eal[ks], bf, acc, 0, 0, 0);
        }
        f32x4 d;
#pragma unroll
        for (int r = 0; r < 4; ++r) d[r] = acc[r] + __shfl_xor(acc[r], 8);
        float sv = 0.f;
        if (l16 < 8) {
            const float kinv = ksf[l16];
#pragma unroll
            for (int r = 0; r < 4; ++r) {
                const int l = wv * 16 + grp * 4 + r;
                const float cv = (bf2f(cax[l16 * 264 + l]) + bf2f(cax[(l16 + 8) * 264 + l])) * kinv;
                sv += d[r] * cv / enl[l];
            }
        }
        sv += __shfl_xor(sv, 16);
        sv += __shfl_xor(sv, 32);
        if (l16 < 8 && grp == 0) red32[wv * 8 + l16] = sv;
    }
#pragma unroll
    for (int pp = 0; pp < 2; ++pp) {
        const int p = wv + pp * 16;
        if (p < 28) {
            int i = 0, rem = p;
            while (rem >= 7 - i) { rem -= 7 - i; ++i; }
            const int j = i + 1 + rem;
            const float mi0 = bf2f(gpk[i * 136 + lane]) + bf2f(gpk[(i + 8) * 136 + lane]);
            const float mi1 = bf2f(gpk[i * 136 + 64 + lane]) + bf2f(gpk[(i + 8) * 136 + 64 + lane]);
            const float mj0 = bf2f(gpk[j * 136 + lane]) + bf2f(gpk[(j + 8) * 136 + lane]);
            const float mj1 = bf2f(gpk[j * 136 + 64 + lane]) + bf2f(gpk[(j + 8) * 136 + 64 + lane]);
            float v = mi0 * mj0 + mi1 * mj1;
#pragma unroll
            for (int o = 32; o; o >>= 1) v += __shfl_xor(v, o);
            if (lane == 0) Ps[p] = v;
        }
    }
    __syncthreads();   // B6
    if (t < 8) {
        float s = 0.f;
#pragma unroll
        for (int w = 0; w < 16; ++w) s += red32[w * 8 + t];
        svals[t] = s;
    }
    __syncthreads();   // B7

    // ===== serial scoring =====
    if (t == 0) {
        int idx[8];
        for (int i = 0; i < 8; ++i) idx[i] = i;
        for (int a = 1; a < 8; ++a) {
            const int key = idx[a];
            const float kv = strv[key];
            int bb = a - 1;
            while (bb >= 0 && strv[idx[bb]] < kv) { idx[bb + 1] = idx[bb]; --bb; }
            idx[bb + 1] = key;
        }
        float best = -1e30f;
        int bestk = 2;
        float cons_sum = 0.f, pair_sum = 0.f;
        for (int kk = 1; kk <= 8; ++kk) {
            const int ni = idx[kk - 1];
            cons_sum += svals[ni];
            for (int a = 0; a < kk - 1; ++a) {
                const int ia = idx[a];
                const int lo = ia < ni ? ia : ni;
                const int hi2 = ia < ni ? ni : ia;
                const int off0 = lo * 7 - lo * (lo - 1) / 2;
                pair_sum += Ps[off0 + hi2 - lo - 1];
            }
            if (kk >= 2) {
                const float cons = cons_sum / (kk * 256.0f);
                const float divv = 1.0f - (2.0f / (kk * (kk - 1))) * pair_sum;
                const float score = 0.5f * cons + 0.5f * divv;
                out[256 + b * 7 + (kk - 2)] = score;
                if (score > best) { best = score; bestk = kk; }
            }
        }
        out[b] = (float)bestk;
    }
}

// ---------------------------------------------------------------------------
extern "C" void kernel_launch(void* const* d_in, const int* in_sizes, int n_in,
                              void* d_out, int out_size, void* d_ws, size_t ws_size,
                              hipStream_t stream) {
    const float* e = (const float*)d_in[0];
    const float* W = (const float*)d_in[1];
    const float* b_init = (const float*)d_in[2];
    float* out = (float*)d_out;

    short* whi = (short*)d_ws;
    short* wlo = whi + 16384;

    hipLaunchKernelGGL(setup_w_kernel, dim3(64), dim3(256), 0, stream, W, whi, wlo);
    hipLaunchKernelGGL(fused_kernel, dim3(NB), dim3(1024), 0, stream,
                       e, b_init, whi, wlo, out);
}

// Round 14
// 46.400 us; speedup vs baseline: 1.5272x; 1.5272x over previous
//
#include <hip/hip_runtime.h>
#include <hip/hip_bf16.h>
#include <math.h>

#define NB 256
#define NL 256
#define NH 128
#define NK 8

typedef __attribute__((ext_vector_type(8))) short bf16x8;
typedef __attribute__((ext_vector_type(4))) short s16x4;
typedef __attribute__((ext_vector_type(4))) float f32x4;

static __device__ __forceinline__ short f2bf(float x) {
    __hip_bfloat16 b = __float2bfloat16(x);
    return *reinterpret_cast<short*>(&b);
}
static __device__ __forceinline__ float bf2f(short s) {
    union { unsigned int u; float f; } v;
    v.u = ((unsigned int)(unsigned short)s) << 16;
    return v.f;
}

#define MFMA __builtin_amdgcn_mfma_f32_16x16x32_bf16

// ---------------------------------------------------------------------------
// Setup: split W into bf16 hi/lo (row-major only).
// ---------------------------------------------------------------------------
__global__ __launch_bounds__(256) void setup_w_kernel(const float* __restrict__ W,
                                                      short* __restrict__ whi,
                                                      short* __restrict__ wlo) {
    const int id = blockIdx.x * 256 + threadIdx.x;
    const float w = W[id];
    const short hi = f2bf(w);
    whi[id] = hi;
    wlo[id] = f2bf(w - bf2f(hi));
}

// ---------------------------------------------------------------------------
// Fused per-batch kernel: 256 blocks x 512 threads (8 waves, <=256 VGPR).
// hat^T staged in LDS via MFMA; hat ROW frags register-resident (2 tiles/wave).
// Iteration = {P1 exp | P2' cap | P6' delta}: 2 barriers/iter, W out of loop.
// ---------------------------------------------------------------------------
__global__ __launch_bounds__(512, 2) void fused_kernel(const float* __restrict__ e,
                                                       const float* __restrict__ b_init,
                                                       const short* __restrict__ whi,
                                                       const short* __restrict__ wlo,
                                                       float* __restrict__ out) {
    const int b = blockIdx.x;
    const int t = threadIdx.x;
    const int lane = t & 63, wv = t >> 6;           // wv in [0,8)
    const int l16 = lane & 15, grp = lane >> 4;

    __shared__ __align__(16) short tThi[128 * 264]; // 67584 B  hat^T hi -> e^T hi
    __shared__ __align__(16) short tTlo[128 * 264]; // 67584 B  hat^T lo -> e^T lo
    __shared__ __align__(16) short cax[16 * 264];   // 8448 B   raw exp hi(0-7)/lo(8-15)
    __shared__ __align__(16) short mpk[16 * 136];   // 4352 B
    __shared__ __align__(16) short cappk[16 * 136]; // 4352 B
    __shared__ __align__(16) short gpk[16 * 136];   // 4352 B
    __shared__ float enl[256];
    __shared__ float red32[64];
    __shared__ __align__(16) float nrmp[64];
    __shared__ float ksf[8], svals[8], strv[8], Ps[28];

    const float* ebg = e + (size_t)b * (NL * NH);

    // ---- per-lane e row-fragments for rows rowA (0-127) and rowB (128-255) ----
    const int rowA = wv * 16 + l16, rowB = 128 + rowA;
    bf16x8 eah[4], eal[4], e2h[4], e2l[4];
    {
        float ssA = 0.f, ssB = 0.f;
#pragma unroll
        for (int ks = 0; ks < 4; ++ks) {
            const int co = ks * 32 + grp * 8;
            const float4 f0 = *(const float4*)&ebg[rowA * 128 + co];
            const float4 f1 = *(const float4*)&ebg[rowA * 128 + co + 4];
            const float4 g0 = *(const float4*)&ebg[rowB * 128 + co];
            const float4 g1 = *(const float4*)&ebg[rowB * 128 + co + 4];
            const float fx[8] = {f0.x, f0.y, f0.z, f0.w, f1.x, f1.y, f1.z, f1.w};
            const float gx[8] = {g0.x, g0.y, g0.z, g0.w, g1.x, g1.y, g1.z, g1.w};
            bf16x8 hv, lv, hv2, lv2;
#pragma unroll
            for (int j = 0; j < 8; ++j) {
                short h = f2bf(fx[j]);
                hv[j] = h; lv[j] = f2bf(fx[j] - bf2f(h));
                ssA += fx[j] * fx[j];
                h = f2bf(gx[j]);
                hv2[j] = h; lv2[j] = f2bf(gx[j] - bf2f(h));
                ssB += gx[j] * gx[j];
            }
            eah[ks] = hv; eal[ks] = lv;
            e2h[ks] = hv2; e2l[ks] = lv2;
        }
        ssA += __shfl_xor(ssA, 16); ssA += __shfl_xor(ssA, 32);
        ssB += __shfl_xor(ssB, 16); ssB += __shfl_xor(ssB, 32);
        if (grp == 0) { enl[rowA] = sqrtf(ssA) + 1e-8f; enl[rowB] = sqrtf(ssB) + 1e-8f; }
    }

    // ---- stage hat^T = W @ e^T via MFMA; wave stages l-cols wv*16 and 128+wv*16 ----
    {
#pragma unroll
        for (int ht = 0; ht < 8; ++ht) {
            const int h0 = ht * 16;
            f32x4 a0 = (f32x4){0.f, 0.f, 0.f, 0.f};
            f32x4 a1 = (f32x4){0.f, 0.f, 0.f, 0.f};
            f32x4 c0 = (f32x4){0.f, 0.f, 0.f, 0.f};
            f32x4 c1 = (f32x4){0.f, 0.f, 0.f, 0.f};
#pragma unroll
            for (int ks = 0; ks < 4; ++ks) {
                const int ao = (h0 + l16) * 128 + ks * 32 + grp * 8;
                const bf16x8 awh = *(const bf16x8*)&whi[ao];
                const bf16x8 awl = *(const bf16x8*)&wlo[ao];
                a0 = MFMA(awh, eah[ks], a0, 0, 0, 0);
                a0 = MFMA(awh, eal[ks], a0, 0, 0, 0);
                a1 = MFMA(awl, eah[ks], a1, 0, 0, 0);
                c0 = MFMA(awh, e2h[ks], c0, 0, 0, 0);
                c0 = MFMA(awh, e2l[ks], c0, 0, 0, 0);
                c1 = MFMA(awl, e2h[ks], c1, 0, 0, 0);
            }
#pragma unroll
            for (int r = 0; r < 4; ++r) {
                const int ho = (h0 + grp * 4 + r) * 264 + wv * 16 + l16;
                float v = a0[r] + a1[r];
                short hv = f2bf(v);
                tThi[ho] = hv;
                tTlo[ho] = f2bf(v - bf2f(hv));
                v = c0[r] + c1[r];
                hv = f2bf(v);
                tThi[ho + 128] = hv;
                tTlo[ho + 128] = f2bf(v - bf2f(hv));
            }
        }
    }

    // ---- logits in regs: lane l16<8 = capsule k; tiles A (l<128) and B ----
    float lrA0 = 0.f, lrA1 = 0.f, lrA2 = 0.f, lrA3 = 0.f;
    float lrB0 = 0.f, lrB1 = 0.f, lrB2 = 0.f, lrB3 = 0.f;
    if (l16 < 8) {
        const float4 ba = *(const float4*)&b_init[(size_t)b * 2048 + l16 * 256 + wv * 16 + grp * 4];
        const float4 bb = *(const float4*)&b_init[(size_t)b * 2048 + l16 * 256 + 128 + wv * 16 + grp * 4];
        lrA0 = ba.x; lrA1 = ba.y; lrA2 = ba.z; lrA3 = ba.w;
        lrB0 = bb.x; lrB1 = bb.y; lrB2 = bb.z; lrB3 = bb.w;
    }
    __syncthreads();   // B0: hat^T ready

    // ---- hat row fragments -> registers (rows rowA and rowB) ----
    bf16x8 hah[4], hal[4], h2h[4], h2l[4];
#pragma unroll
    for (int ks = 0; ks < 4; ++ks) {
#pragma unroll
        for (int j = 0; j < 8; ++j) {
            const int hh = ks * 32 + grp * 8 + j;
            hah[ks][j] = tThi[hh * 264 + rowA];
            hal[ks][j] = tTlo[hh * 264 + rowA];
            h2h[ks][j] = tThi[hh * 264 + rowB];
            h2l[ks][j] = tTlo[hh * 264 + rowB];
        }
    }

    for (int iter = 0; iter < 3; ++iter) {
        // ===== P1: raw exp, both tiles; ksum partials; cax write =====
        {
            const float a0 = expf(lrA0), a1 = expf(lrA1), a2 = expf(lrA2), a3 = expf(lrA3);
            const float b0 = expf(lrB0), b1 = expf(lrB1), b2 = expf(lrB2), b3 = expf(lrB3);
            float s4 = a0 + a1 + a2 + a3 + b0 + b1 + b2 + b3;
            s4 += __shfl_xor(s4, 16);
            s4 += __shfl_xor(s4, 32);
            if (l16 < 8 && grp == 0) red32[wv * 8 + l16] = s4;
            if (l16 < 8) {
                const int lb = wv * 16 + grp * 4;
                const float ca[4] = {a0, a1, a2, a3};
                const float cb[4] = {b0, b1, b2, b3};
                s16x4 hisA, losA, hisB, losB;
#pragma unroll
                for (int j = 0; j < 4; ++j) {
                    short h = f2bf(ca[j]);
                    hisA[j] = h; losA[j] = f2bf(ca[j] - bf2f(h));
                    h = f2bf(cb[j]);
                    hisB[j] = h; losB[j] = f2bf(cb[j] - bf2f(h));
                }
                *(s16x4*)&cax[l16 * 264 + lb] = hisA;
                *(s16x4*)&cax[(l16 + 8) * 264 + lb] = losA;
                *(s16x4*)&cax[l16 * 264 + 128 + lb] = hisB;
                *(s16x4*)&cax[(l16 + 8) * 264 + 128 + lb] = losB;
            }
        }
        __syncthreads();   // B1

        // ===== P2': cap = (exp @ hat^T) * (1/ksum) + norm partials =====
        {
            float inv = 0.f;
            if (l16 < 8) {
                float kss = 0.f;
#pragma unroll
                for (int w = 0; w < 8; ++w) kss += red32[w * 8 + l16];
                inv = 1.0f / kss;
            }
            const int n0 = wv * 16;
            f32x4 ac0 = (f32x4){0.f, 0.f, 0.f, 0.f};
            f32x4 ac1 = (f32x4){0.f, 0.f, 0.f, 0.f};
#pragma unroll
            for (int ks = 0; ks < 4; ++ks) {
                const bf16x8 af = *(const bf16x8*)&cax[l16 * 264 + ks * 32 + grp * 8];
                const bf16x8 bh = *(const bf16x8*)&tThi[(n0 + l16) * 264 + ks * 32 + grp * 8];
                const bf16x8 bl = *(const bf16x8*)&tTlo[(n0 + l16) * 264 + ks * 32 + grp * 8];
                ac0 = MFMA(af, bh, ac0, 0, 0, 0);
                ac0 = MFMA(af, bl, ac0, 0, 0, 0);
            }
#pragma unroll
            for (int ks = 4; ks < 8; ++ks) {
                const bf16x8 af = *(const bf16x8*)&cax[l16 * 264 + ks * 32 + grp * 8];
                const bf16x8 bh = *(const bf16x8*)&tThi[(n0 + l16) * 264 + ks * 32 + grp * 8];
                const bf16x8 bl = *(const bf16x8*)&tTlo[(n0 + l16) * 264 + ks * 32 + grp * 8];
                ac1 = MFMA(af, bh, ac1, 0, 0, 0);
                ac1 = MFMA(af, bl, ac1, 0, 0, 0);
            }
            const f32x4 acc = ac0 + ac1;
            f32x4 cs;
            float pn[4];
#pragma unroll
            for (int r = 0; r < 4; ++r) {
                cs[r] = acc[r] + __shfl_xor(acc[r], 32);
                cs[r] *= __shfl(inv, grp * 4 + r);
                float p2 = cs[r] * cs[r];
                p2 += __shfl_xor(p2, 1);
                p2 += __shfl_xor(p2, 2);
                p2 += __shfl_xor(p2, 4);
                p2 += __shfl_xor(p2, 8);
                pn[r] = p2;
            }
            if (l16 == 0 && grp < 2) {
                float4 pv;
                pv.x = pn[0]; pv.y = pn[1]; pv.z = pn[2]; pv.w = pn[3];
                *(float4*)&nrmp[wv * 8 + grp * 4] = pv;
            }
            if (iter < 2 && grp < 2) {
#pragma unroll
                for (int r = 0; r < 4; ++r) {
                    const int k = grp * 4 + r, h = n0 + l16;
                    const short hv = f2bf(cs[r]);
                    cappk[k * 136 + h] = hv;
                    cappk[(k + 8) * 136 + h] = f2bf(cs[r] - bf2f(hv));
                }
            }
            if (iter == 2 && wv == 0 && grp == 0 && l16 < 8) ksf[l16] = inv;
        }
        __syncthreads();   // B2

        if (iter < 2) {
            // ===== P6': logits += squash_sc * (hat_rows . cap), both tiles =====
            float sc;
            {
                float n = 0.f;
#pragma unroll
                for (int w = 0; w < 8; ++w) n += nrmp[w * 8 + (l16 & 7)];
                sc = n / (1.0f + n) / sqrtf(n + 1e-9f);
            }
            f32x4 accA = (f32x4){0.f, 0.f, 0.f, 0.f};
            f32x4 accB = (f32x4){0.f, 0.f, 0.f, 0.f};
#pragma unroll
            for (int ks = 0; ks < 4; ++ks) {
                const bf16x8 bf = *(const bf16x8*)&cappk[l16 * 136 + ks * 32 + grp * 8];
                accA = MFMA(hah[ks], bf, accA, 0, 0, 0);
                accA = MFMA(hal[ks], bf, accA, 0, 0, 0);
                accB = MFMA(h2h[ks], bf, accB, 0, 0, 0);
                accB = MFMA(h2l[ks], bf, accB, 0, 0, 0);
            }
            lrA0 += sc * (accA[0] + __shfl_xor(accA[0], 8));
            lrA1 += sc * (accA[1] + __shfl_xor(accA[1], 8));
            lrA2 += sc * (accA[2] + __shfl_xor(accA[2], 8));
            lrA3 += sc * (accA[3] + __shfl_xor(accA[3], 8));
            lrB0 += sc * (accB[0] + __shfl_xor(accB[0], 8));
            lrB1 += sc * (accB[1] + __shfl_xor(accB[1], 8));
            lrB2 += sc * (accB[2] + __shfl_xor(accB[2], 8));
            lrB3 += sc * (accB[3] + __shfl_xor(accB[3], 8));
        }
    }

    // ===== strength ∥ restage e^T into tT (hat^T dead after B2 of iter 2) =====
    if (wv == 0 && lane < 8) {
        float n = 0.f;
#pragma unroll
        for (int w = 0; w < 8; ++w) n += nrmp[w * 8 + lane];
        strv[lane] = n / (1.0f + n) * sqrtf(n) / sqrtf(n + 1e-9f);
    }
#pragma unroll
    for (int i = 0; i < 8; ++i) {
        const int p = i * 512 + t;
        const int h = p & 127, c = p >> 7;
        float le[8];
#pragma unroll
        for (int j = 0; j < 8; ++j) le[j] = ebg[(c * 8 + j) * 128 + h];
        bf16x8 hv, lv;
#pragma unroll
        for (int j = 0; j < 8; ++j) {
            const short s = f2bf(le[j]);
            hv[j] = s;
            lv[j] = f2bf(le[j] - bf2f(s));
        }
        *(bf16x8*)&tThi[h * 264 + c * 8] = hv;
        *(bf16x8*)&tTlo[h * 264 + c * 8] = lv;
    }
    __syncthreads();   // B3

    // ===== m_raw = exp_final @ e (MFMA over restaged e^T) =====
    {
        const int n0 = wv * 16;
        f32x4 ac0 = (f32x4){0.f, 0.f, 0.f, 0.f};
        f32x4 ac1 = (f32x4){0.f, 0.f, 0.f, 0.f};
#pragma unroll
        for (int ks = 0; ks < 4; ++ks) {
            const bf16x8 af = *(const bf16x8*)&cax[l16 * 264 + ks * 32 + grp * 8];
            const bf16x8 bh = *(const bf16x8*)&tThi[(n0 + l16) * 264 + ks * 32 + grp * 8];
            const bf16x8 bl = *(const bf16x8*)&tTlo[(n0 + l16) * 264 + ks * 32 + grp * 8];
            ac0 = MFMA(af, bh, ac0, 0, 0, 0);
            ac0 = MFMA(af, bl, ac0, 0, 0, 0);
        }
#pragma unroll
        for (int ks = 4; ks < 8; ++ks) {
            const bf16x8 af = *(const bf16x8*)&cax[l16 * 264 + ks * 32 + grp * 8];
            const bf16x8 bh = *(const bf16x8*)&tThi[(n0 + l16) * 264 + ks * 32 + grp * 8];
            const bf16x8 bl = *(const bf16x8*)&tTlo[(n0 + l16) * 264 + ks * 32 + grp * 8];
            ac1 = MFMA(af, bh, ac1, 0, 0, 0);
            ac1 = MFMA(af, bl, ac1, 0, 0, 0);
        }
        const f32x4 acc = ac0 + ac1;
        f32x4 ms;
#pragma unroll
        for (int r = 0; r < 4; ++r) ms[r] = acc[r] + __shfl_xor(acc[r], 32);
        if (grp < 2) {
#pragma unroll
            for (int r = 0; r < 4; ++r) {
                const int k = grp * 4 + r, h = n0 + l16;
                const short hv = f2bf(ms[r]);
                mpk[k * 136 + h] = hv;
                mpk[(k + 8) * 136 + h] = f2bf(ms[r] - bf2f(hv));
            }
        }
    }
    __syncthreads();   // B4

    // ===== mu_n = m / (||m|| + 1e-8) -> gpk =====
    {
        const int k = wv;
        float x0 = bf2f(mpk[k * 136 + lane]) + bf2f(mpk[(k + 8) * 136 + lane]);
        float x1 = bf2f(mpk[k * 136 + 64 + lane]) + bf2f(mpk[(k + 8) * 136 + 64 + lane]);
        float s = x0 * x0 + x1 * x1;
#pragma unroll
        for (int o = 32; o; o >>= 1) s += __shfl_xor(s, o);
        const float nv = sqrtf(s) + 1e-8f;
        x0 /= nv; x1 /= nv;
        short hv = f2bf(x0);
        gpk[k * 136 + lane] = hv;
        gpk[(k + 8) * 136 + lane] = f2bf(x0 - bf2f(hv));
        hv = f2bf(x1);
        gpk[k * 136 + 64 + lane] = hv;
        gpk[(k + 8) * 136 + 64 + lane] = f2bf(x1 - bf2f(hv));
    }
    __syncthreads();   // B5

    // ===== P9: dot = e . mu (A=e regs, both tiles), weight by c/enl ∥ Gram =====
    {
        f32x4 accA = (f32x4){0.f, 0.f, 0.f, 0.f};
        f32x4 accB = (f32x4){0.f, 0.f, 0.f, 0.f};
#pragma unroll
        for (int ks = 0; ks < 4; ++ks) {
            const bf16x8 bf = *(const bf16x8*)&gpk[l16 * 136 + ks * 32 + grp * 8];
            accA = MFMA(eah[ks], bf, accA, 0, 0, 0);
            accA = MFMA(eal[ks], bf, accA, 0, 0, 0);
            accB = MFMA(e2h[ks], bf, accB, 0, 0, 0);
            accB = MFMA(e2l[ks], bf, accB, 0, 0, 0);
        }
        float sv = 0.f;
        if (l16 < 8) {
            const float kinv = ksf[l16];
#pragma unroll
            for (int r = 0; r < 4; ++r) {
                const float dA = accA[r] + __shfl_xor(accA[r], 8);
                const float dB = accB[r] + __shfl_xor(accB[r], 8);
                const int lA = wv * 16 + grp * 4 + r;
                const int lB = lA + 128;
                const float cvA = (bf2f(cax[l16 * 264 + lA]) + bf2f(cax[(l16 + 8) * 264 + lA])) * kinv;
                const float cvB = (bf2f(cax[l16 * 264 + lB]) + bf2f(cax[(l16 + 8) * 264 + lB])) * kinv;
                sv += dA * cvA / enl[lA] + dB * cvB / enl[lB];
            }
        }
        sv += __shfl_xor(sv, 16);
        sv += __shfl_xor(sv, 32);
        if (l16 < 8 && grp == 0) red32[wv * 8 + l16] = sv;
    }
#pragma unroll
    for (int pp = 0; pp < 4; ++pp) {
        const int p = wv + pp * 8;
        if (p < 28) {
            int i = 0, rem = p;
            while (rem >= 7 - i) { rem -= 7 - i; ++i; }
            const int j = i + 1 + rem;
            const float mi0 = bf2f(gpk[i * 136 + lane]) + bf2f(gpk[(i + 8) * 136 + lane]);
            const float mi1 = bf2f(gpk[i * 136 + 64 + lane]) + bf2f(gpk[(i + 8) * 136 + 64 + lane]);
            const float mj0 = bf2f(gpk[j * 136 + lane]) + bf2f(gpk[(j + 8) * 136 + lane]);
            const float mj1 = bf2f(gpk[j * 136 + 64 + lane]) + bf2f(gpk[(j + 8) * 136 + 64 + lane]);
            float v = mi0 * mj0 + mi1 * mj1;
#pragma unroll
            for (int o = 32; o; o >>= 1) v += __shfl_xor(v, o);
            if (lane == 0) Ps[p] = v;
        }
    }
    __syncthreads();   // B6
    if (t < 8) {
        float s = 0.f;
#pragma unroll
        for (int w = 0; w < 8; ++w) s += red32[w * 8 + t];
        svals[t] = s;
    }
    __syncthreads();   // B7

    // ===== serial scoring =====
    if (t == 0) {
        int idx[8];
        for (int i = 0; i < 8; ++i) idx[i] = i;
        for (int a = 1; a < 8; ++a) {
            const int key = idx[a];
            const float kv = strv[key];
            int bb = a - 1;
            while (bb >= 0 && strv[idx[bb]] < kv) { idx[bb + 1] = idx[bb]; --bb; }
            idx[bb + 1] = key;
        }
        float best = -1e30f;
        int bestk = 2;
        float cons_sum = 0.f, pair_sum = 0.f;
        for (int kk = 1; kk <= 8; ++kk) {
            const int ni = idx[kk - 1];
            cons_sum += svals[ni];
            for (int a = 0; a < kk - 1; ++a) {
                const int ia = idx[a];
                const int lo = ia < ni ? ia : ni;
                const int hi2 = ia < ni ? ni : ia;
                const int off0 = lo * 7 - lo * (lo - 1) / 2;
                pair_sum += Ps[off0 + hi2 - lo - 1];
            }
            if (kk >= 2) {
                const float cons = cons_sum / (kk * 256.0f);
                const float divv = 1.0f - (2.0f / (kk * (kk - 1))) * pair_sum;
                const float score = 0.5f * cons + 0.5f * divv;
                out[256 + b * 7 + (kk - 2)] = score;
                if (score > best) { best = score; bestk = kk; }
            }
        }
        out[b] = (float)bestk;
    }
}

// ---------------------------------------------------------------------------
extern "C" void kernel_launch(void* const* d_in, const int* in_sizes, int n_in,
                              void* d_out, int out_size, void* d_ws, size_t ws_size,
                              hipStream_t stream) {
    const float* e = (const float*)d_in[0];
    const float* W = (const float*)d_in[1];
    const float* b_init = (const float*)d_in[2];
    float* out = (float*)d_out;

    short* whi = (short*)d_ws;
    short* wlo = whi + 16384;

    hipLaunchKernelGGL(setup_w_kernel, dim3(64), dim3(256), 0, stream, W, whi, wlo);
    hipLaunchKernelGGL(fused_kernel, dim3(NB), dim3(512), 0, stream,
                       e, b_init, whi, wlo, out);
}

// Round 17
// 39.274 us; speedup vs baseline: 1.8043x; 1.1815x over previous
//
#include <hip/hip_runtime.h>
#include <hip/hip_bf16.h>
#include <math.h>

#define NB 256
#define NL 256
#define NH 128
#define NK 8

typedef __attribute__((ext_vector_type(8))) short bf16x8;
typedef __attribute__((ext_vector_type(4))) short s16x4;
typedef __attribute__((ext_vector_type(4))) float f32x4;

static __device__ __forceinline__ short f2bf(float x) {
    __hip_bfloat16 b = __float2bfloat16(x);
    return *reinterpret_cast<short*>(&b);
}
static __device__ __forceinline__ float bf2f(short s) {
    union { unsigned int u; float f; } v;
    v.u = ((unsigned int)(unsigned short)s) << 16;
    return v.f;
}

#define MFMA __builtin_amdgcn_mfma_f32_16x16x32_bf16

// ---------------------------------------------------------------------------
// Setup: split W into bf16 hi/lo + transposed copies (global, L2/L3-hot).
// ---------------------------------------------------------------------------
__global__ __launch_bounds__(256) void setup_w_kernel(const float* __restrict__ W,
                                                      short* __restrict__ whi,
                                                      short* __restrict__ wlo,
                                                      short* __restrict__ wthi,
                                                      short* __restrict__ wtlo) {
    const int id = blockIdx.x * 256 + threadIdx.x;   // h*128 + j
    const int h = id >> 7, j = id & 127;
    const float w = W[id];
    const short hi = f2bf(w);
    const short lo = f2bf(w - bf2f(hi));
    whi[id] = hi;
    wlo[id] = lo;
    wthi[j * 128 + h] = hi;
    wtlo[j * 128 + h] = lo;
}

// ---------------------------------------------------------------------------
// Fused per-batch kernel: 256 blocks x 1024 threads (16 waves).
// EXACTLY round-12's verified structure, with the standalone P1 phase fused:
// iter-0 exp hoisted into staging (ordered by B0); iter N+1 exp computed at
// the end of P6 (register work), barrier after. One fewer phase per iter.
// ---------------------------------------------------------------------------
__global__ __launch_bounds__(1024) void fused_kernel(const float* __restrict__ e,
                                                     const float* __restrict__ b_init,
                                                     const short* __restrict__ whi,
                                                     const short* __restrict__ wlo,
                                                     const short* __restrict__ wthi,
                                                     const short* __restrict__ wtlo,
                                                     float* __restrict__ out) {
    const int b = blockIdx.x;
    const int t = threadIdx.x;
    const int lane = t & 63, wv = t >> 6;
    const int l16 = lane & 15, grp = lane >> 4;

    __shared__ __align__(16) short eThi[128 * 264]; // 67584 B  e^T hi
    __shared__ __align__(16) short eTlo[128 * 264]; // 67584 B  e^T lo
    __shared__ __align__(16) short cax[16 * 264];   // 8448 B   raw exp rows 0-7 hi, 8-15 lo
    __shared__ __align__(16) short mpk[16 * 136];   // 4352 B   m_raw hi/lo
    __shared__ __align__(16) short cappk[16 * 136]; // 4352 B   cap (ksum-scaled) hi/lo
    __shared__ __align__(16) short gpk[16 * 136];   // 4352 B   g / mu hi/lo
    __shared__ float enl[256];                      // 1024 B
    __shared__ float red32[128];                    // 512 B
    __shared__ __align__(16) float nrmp[64];        // 256 B
    __shared__ float ksf[8], svals[8], strv[8], Ps[28];

    const float* ebg = e + (size_t)b * (NL * NH);

    // ---- per-lane e row-fragments (P6/P9 A-operand) + row norms ----
    bf16x8 eah[4], eal[4];
    {
        const int row = wv * 16 + l16;
        float ss = 0.f;
#pragma unroll
        for (int ks = 0; ks < 4; ++ks) {
            const float4 f0 = *(const float4*)&ebg[row * 128 + ks * 32 + grp * 8];
            const float4 f1 = *(const float4*)&ebg[row * 128 + ks * 32 + grp * 8 + 4];
            const float fx[8] = {f0.x, f0.y, f0.z, f0.w, f1.x, f1.y, f1.z, f1.w};
            bf16x8 hv, lv;
#pragma unroll
            for (int j = 0; j < 8; ++j) {
                const short h = f2bf(fx[j]);
                hv[j] = h;
                lv[j] = f2bf(fx[j] - bf2f(h));
                ss += fx[j] * fx[j];
            }
            eah[ks] = hv;
            eal[ks] = lv;
        }
        ss += __shfl_xor(ss, 16);
        ss += __shfl_xor(ss, 32);
        if (grp == 0) enl[row] = sqrtf(ss) + 1e-8f;
    }

    // ---- stage e^T (bf16 hi/lo): coalesced column-gather ----
#pragma unroll
    for (int i = 0; i < 4; ++i) {
        const int p = i * 1024 + t;
        const int h = p & 127, c = p >> 7;
        float le[8];
#pragma unroll
        for (int j = 0; j < 8; ++j) le[j] = ebg[(c * 8 + j) * 128 + h];
        bf16x8 hv, lv;
#pragma unroll
        for (int j = 0; j < 8; ++j) {
            const short s = f2bf(le[j]);
            hv[j] = s;
            lv[j] = f2bf(le[j] - bf2f(s));
        }
        *(bf16x8*)&eThi[h * 264 + c * 8] = hv;
        *(bf16x8*)&eTlo[h * 264 + c * 8] = lv;
    }

    // ---- logits in regs: lane l16<8 = capsule k, l = wv*16+grp*4+r ----
    float lr0 = 0.f, lr1 = 0.f, lr2 = 0.f, lr3 = 0.f;
    if (l16 < 8) {
        const float4 bi = *(const float4*)&b_init[(size_t)b * 2048 + l16 * 256 + wv * 16 + grp * 4];
        lr0 = bi.x; lr1 = bi.y; lr2 = bi.z; lr3 = bi.w;
    }

    // ---- hoisted iter-0 P1: raw exp (no norm, no max-sub; f32-safe) ----
    {
        const float e0 = expf(lr0), e1 = expf(lr1);
        const float e2 = expf(lr2), e3 = expf(lr3);
        float s4 = e0 + e1 + e2 + e3;
        s4 += __shfl_xor(s4, 16);
        s4 += __shfl_xor(s4, 32);
        if (l16 < 8 && grp == 0) red32[wv * 8 + l16] = s4;
        if (l16 < 8) {
            const int lb = wv * 16 + grp * 4;
            const float cv[4] = {e0, e1, e2, e3};
            s16x4 his, los;
#pragma unroll
            for (int j = 0; j < 4; ++j) {
                const short h = f2bf(cv[j]);
                his[j] = h;
                los[j] = f2bf(cv[j] - bf2f(h));
            }
            *(s16x4*)&cax[l16 * 264 + lb] = his;
            *(s16x4*)&cax[(l16 + 8) * 264 + lb] = los;
        }
    }
    __syncthreads();   // B0: staging + iter-0 exp ready

    for (int iter = 0; iter < 3; ++iter) {
        // ===== P2: m_raw = exp @ e  (A=[exp_hi;exp_lo], B=eT hi/lo, waves 0-7) =====
        if (wv < 8) {
            const int n0 = wv * 16;
            f32x4 ac0 = (f32x4){0.f, 0.f, 0.f, 0.f};
            f32x4 ac1 = (f32x4){0.f, 0.f, 0.f, 0.f};
#pragma unroll
            for (int ks = 0; ks < 4; ++ks) {
                const bf16x8 af = *(const bf16x8*)&cax[l16 * 264 + ks * 32 + grp * 8];
                const bf16x8 bh = *(const bf16x8*)&eThi[(n0 + l16) * 264 + ks * 32 + grp * 8];
                const bf16x8 bl = *(const bf16x8*)&eTlo[(n0 + l16) * 264 + ks * 32 + grp * 8];
                ac0 = MFMA(af, bh, ac0, 0, 0, 0);
                ac0 = MFMA(af, bl, ac0, 0, 0, 0);
            }
#pragma unroll
            for (int ks = 4; ks < 8; ++ks) {
                const bf16x8 af = *(const bf16x8*)&cax[l16 * 264 + ks * 32 + grp * 8];
                const bf16x8 bh = *(const bf16x8*)&eThi[(n0 + l16) * 264 + ks * 32 + grp * 8];
                const bf16x8 bl = *(const bf16x8*)&eTlo[(n0 + l16) * 264 + ks * 32 + grp * 8];
                ac1 = MFMA(af, bh, ac1, 0, 0, 0);
                ac1 = MFMA(af, bl, ac1, 0, 0, 0);
            }
            const f32x4 acc = ac0 + ac1;
            f32x4 ms;
#pragma unroll
            for (int r = 0; r < 4; ++r) ms[r] = acc[r] + __shfl_xor(acc[r], 32);
            if (grp < 2) {
#pragma unroll
                for (int r = 0; r < 4; ++r) {
                    const int k = grp * 4 + r, h = n0 + l16;
                    const short hv = f2bf(ms[r]);
                    mpk[k * 136 + h] = hv;
                    mpk[(k + 8) * 136 + h] = f2bf(ms[r] - bf2f(hv));
                }
            }
        }
        __syncthreads();   // B2

        // ===== P3: cap = (m_raw @ W^T) * (1/ksum)  + norm partials =====
        if (wv < 8) {
            float inv = 0.f;
            if (l16 < 8) {
                float kss = 0.f;
#pragma unroll
                for (int w = 0; w < 16; ++w) kss += red32[w * 8 + l16];
                inv = 1.0f / kss;
            }
            const int n0 = wv * 16;
            f32x4 acc = (f32x4){0.f, 0.f, 0.f, 0.f};
#pragma unroll
            for (int ks = 0; ks < 4; ++ks) {
                const bf16x8 af = *(const bf16x8*)&mpk[l16 * 136 + ks * 32 + grp * 8];
                const int bo = (n0 + l16) * 128 + ks * 32 + grp * 8;
                acc = MFMA(af, *(const bf16x8*)&whi[bo], acc, 0, 0, 0);
                acc = MFMA(af, *(const bf16x8*)&wlo[bo], acc, 0, 0, 0);
            }
            f32x4 cs;
            float pn[4];
#pragma unroll
            for (int r = 0; r < 4; ++r) {
                cs[r] = acc[r] + __shfl_xor(acc[r], 32);
                cs[r] *= __shfl(inv, grp * 4 + r);
                float p2 = cs[r] * cs[r];
                p2 += __shfl_xor(p2, 1);
                p2 += __shfl_xor(p2, 2);
                p2 += __shfl_xor(p2, 4);
                p2 += __shfl_xor(p2, 8);
                pn[r] = p2;
            }
            if (l16 == 0 && grp < 2) {
                float4 pv;
                pv.x = pn[0]; pv.y = pn[1]; pv.z = pn[2]; pv.w = pn[3];
                *(float4*)&nrmp[wv * 8 + grp * 4] = pv;
            }
            if (iter < 2 && grp < 2) {
#pragma unroll
                for (int r = 0; r < 4; ++r) {
                    const int k2 = grp * 4 + r, h = n0 + l16;
                    const short hv = f2bf(cs[r]);
                    cappk[k2 * 136 + h] = hv;
                    cappk[(k2 + 8) * 136 + h] = f2bf(cs[r] - bf2f(hv));
                }
            }
            if (iter == 2 && wv == 0 && grp == 0 && l16 < 8) ksf[l16] = inv;
        }
        __syncthreads();   // B3

        if (iter < 2) {
            // ===== P5: g = (cap @ W) * squash_scale(k) =====
            if (wv < 8) {
                float sc = 0.f;
                if (l16 < 8) {
                    float n = 0.f;
#pragma unroll
                    for (int w = 0; w < 8; ++w) n += nrmp[w * 8 + l16];
                    sc = n / (1.0f + n) / sqrtf(n + 1e-9f);
                }
                const int n0 = wv * 16;
                f32x4 acc = (f32x4){0.f, 0.f, 0.f, 0.f};
#pragma unroll
                for (int ks = 0; ks < 4; ++ks) {
                    const bf16x8 af = *(const bf16x8*)&cappk[l16 * 136 + ks * 32 + grp * 8];
                    const int bo = (n0 + l16) * 128 + ks * 32 + grp * 8;
                    acc = MFMA(af, *(const bf16x8*)&wthi[bo], acc, 0, 0, 0);
                    acc = MFMA(af, *(const bf16x8*)&wtlo[bo], acc, 0, 0, 0);
                }
                f32x4 gs;
#pragma unroll
                for (int r = 0; r < 4; ++r) {
                    gs[r] = acc[r] + __shfl_xor(acc[r], 32);
                    gs[r] *= __shfl(sc, grp * 4 + r);
                }
                if (grp < 2) {
#pragma unroll
                    for (int r = 0; r < 4; ++r) {
                        const int k2 = grp * 4 + r, h = n0 + l16;
                        const short hv = f2bf(gs[r]);
                        gpk[k2 * 136 + h] = hv;
                        gpk[(k2 + 8) * 136 + h] = f2bf(gs[r] - bf2f(hv));
                    }
                }
            }
            __syncthreads();   // B4

            // ===== P6: logits += e . g  (A=e regs, C=logits)  + fused P1 =====
            {
                f32x4 acc;
                acc[0] = (l16 < 8) ? lr0 : 0.f;
                acc[1] = (l16 < 8) ? lr1 : 0.f;
                acc[2] = (l16 < 8) ? lr2 : 0.f;
                acc[3] = (l16 < 8) ? lr3 : 0.f;
#pragma unroll
                for (int ks = 0; ks < 4; ++ks) {
                    const bf16x8 bf = *(const bf16x8*)&gpk[l16 * 136 + ks * 32 + grp * 8];
                    acc = MFMA(eah[ks], bf, acc, 0, 0, 0);
                    acc = MFMA(eal[ks], bf, acc, 0, 0, 0);
                }
                lr0 = acc[0] + __shfl_xor(acc[0], 8);
                lr1 = acc[1] + __shfl_xor(acc[1], 8);
                lr2 = acc[2] + __shfl_xor(acc[2], 8);
                lr3 = acc[3] + __shfl_xor(acc[3], 8);
                // fused P1 for iter+1 (register work; barrier below orders writes)
                const float e0 = expf(lr0), e1 = expf(lr1);
                const float e2 = expf(lr2), e3 = expf(lr3);
                float s4 = e0 + e1 + e2 + e3;
                s4 += __shfl_xor(s4, 16);
                s4 += __shfl_xor(s4, 32);
                if (l16 < 8 && grp == 0) red32[wv * 8 + l16] = s4;
                if (l16 < 8) {
                    const int lb = wv * 16 + grp * 4;
                    const float cv[4] = {e0, e1, e2, e3};
                    s16x4 his, los;
#pragma unroll
                    for (int j = 0; j < 4; ++j) {
                        const short h = f2bf(cv[j]);
                        his[j] = h;
                        los[j] = f2bf(cv[j] - bf2f(h));
                    }
                    *(s16x4*)&cax[l16 * 264 + lb] = his;
                    *(s16x4*)&cax[(l16 + 8) * 264 + lb] = los;
                }
            }
            __syncthreads();   // B5 (replaces round-12's P1->B1)
        }
    }

    // ===== strength (wave 8) ∥ mu_n -> gpk (waves 0-7) =====
    if (wv == 8 && lane < 8) {
        float n = 0.f;
#pragma unroll
        for (int w = 0; w < 8; ++w) n += nrmp[w * 8 + lane];
        strv[lane] = n / (1.0f + n) * sqrtf(n) / sqrtf(n + 1e-9f);
    }
    if (wv < 8) {
        const int k = wv;
        float x0 = bf2f(mpk[k * 136 + lane]) + bf2f(mpk[(k + 8) * 136 + lane]);
        float x1 = bf2f(mpk[k * 136 + 64 + lane]) + bf2f(mpk[(k + 8) * 136 + 64 + lane]);
        float s = x0 * x0 + x1 * x1;
#pragma unroll
        for (int o = 32; o; o >>= 1) s += __shfl_xor(s, o);
        const float nv = sqrtf(s) + 1e-8f;   // scale-invariant: m_raw/||m_raw||
        x0 /= nv; x1 /= nv;
        short hv = f2bf(x0);
        gpk[k * 136 + lane] = hv;
        gpk[(k + 8) * 136 + lane] = f2bf(x0 - bf2f(hv));
        hv = f2bf(x1);
        gpk[k * 136 + 64 + lane] = hv;
        gpk[(k + 8) * 136 + 64 + lane] = f2bf(x1 - bf2f(hv));
    }
    __syncthreads();   // B6

    // ===== P9: dot = e . mu (MFMA), weight by c/enl ∥ Gram pairs =====
    {
        f32x4 acc = (f32x4){0.f, 0.f, 0.f, 0.f};
#pragma unroll
        for (int ks = 0; ks < 4; ++ks) {
            const bf16x8 bf = *(const bf16x8*)&gpk[l16 * 136 + ks * 32 + grp * 8];
            acc = MFMA(eah[ks], bf, acc, 0, 0, 0);
            acc = MFMA(eal[ks], bf, acc, 0, 0, 0);
        }
        f32x4 d;
#pragma unroll
        for (int r = 0; r < 4; ++r) d[r] = acc[r] + __shfl_xor(acc[r], 8);
        float sv = 0.f;
        if (l16 < 8) {
            const float kinv = ksf[l16];
#pragma unroll
            for (int r = 0; r < 4; ++r) {
                const int l = wv * 16 + grp * 4 + r;
                const float cv = (bf2f(cax[l16 * 264 + l]) + bf2f(cax[(l16 + 8) * 264 + l])) * kinv;
                sv += d[r] * cv / enl[l];
            }
        }
        sv += __shfl_xor(sv, 16);
        sv += __shfl_xor(sv, 32);
        if (l16 < 8 && grp == 0) red32[wv * 8 + l16] = sv;
    }
#pragma unroll
    for (int pp = 0; pp < 2; ++pp) {
        const int p = wv + pp * 16;
        if (p < 28) {
            int i = 0, rem = p;
            while (rem >= 7 - i) { rem -= 7 - i; ++i; }
            const int j = i + 1 + rem;
            const float mi0 = bf2f(gpk[i * 136 + lane]) + bf2f(gpk[(i + 8) * 136 + lane]);
            const float mi1 = bf2f(gpk[i * 136 + 64 + lane]) + bf2f(gpk[(i + 8) * 136 + 64 + lane]);
            const float mj0 = bf2f(gpk[j * 136 + lane]) + bf2f(gpk[(j + 8) * 136 + lane]);
            const float mj1 = bf2f(gpk[j * 136 + 64 + lane]) + bf2f(gpk[(j + 8) * 136 + 64 + lane]);
            float v = mi0 * mj0 + mi1 * mj1;
#pragma unroll
            for (int o = 32; o; o >>= 1) v += __shfl_xor(v, o);
            if (lane == 0) Ps[p] = v;
        }
    }
    __syncthreads();   // B7
    if (t < 8) {
        float s = 0.f;
#pragma unroll
        for (int w = 0; w < 16; ++w) s += red32[w * 8 + t];
        svals[t] = s;
    }
    __syncthreads();   // B8

    // ===== serial scoring =====
    if (t == 0) {
        int idx[8];
        for (int i = 0; i < 8; ++i) idx[i] = i;
        for (int a = 1; a < 8; ++a) {
            const int key = idx[a];
            const float kv = strv[key];
            int bb = a - 1;
            while (bb >= 0 && strv[idx[bb]] < kv) { idx[bb + 1] = idx[bb]; --bb; }
            idx[bb + 1] = key;
        }
        float best = -1e30f;
        int bestk = 2;
        float cons_sum = 0.f, pair_sum = 0.f;
        for (int kk = 1; kk <= 8; ++kk) {
            const int ni = idx[kk - 1];
            cons_sum += svals[ni];
            for (int a = 0; a < kk - 1; ++a) {
                const int ia = idx[a];
                const int lo = ia < ni ? ia : ni;
                const int hi2 = ia < ni ? ni : ia;
                const int off0 = lo * 7 - lo * (lo - 1) / 2;
                pair_sum += Ps[off0 + hi2 - lo - 1];
            }
            if (kk >= 2) {
                const float cons = cons_sum / (kk * 256.0f);
                const float divv = 1.0f - (2.0f / (kk * (kk - 1))) * pair_sum;
                const float score = 0.5f * cons + 0.5f * divv;
                out[256 + b * 7 + (kk - 2)] = score;
                if (score > best) { best = score; bestk = kk; }
            }
        }
        out[b] = (float)bestk;
    }
}

// ---------------------------------------------------------------------------
extern "C" void kernel_launch(void* const* d_in, const int* in_sizes, int n_in,
                              void* d_out, int out_size, void* d_ws, size_t ws_size,
                              hipStream_t stream) {
    const float* e = (const float*)d_in[0];
    const float* W = (const float*)d_in[1];
    const float* b_init = (const float*)d_in[2];
    float* out = (float*)d_out;

    short* whi = (short*)d_ws;
    short* wlo = whi + 16384;
    short* wthi = wlo + 16384;
    short* wtlo = wthi + 16384;

    hipLaunchKernelGGL(setup_w_kernel, dim3(64), dim3(256), 0, stream, W, whi, wlo, wthi, wtlo);
    hipLaunchKernelGGL(fused_kernel, dim3(NB), dim3(1024), 0, stream,
                       e, b_init, whi, wlo, wthi, wtlo, out);
}

// Round 18
// 38.176 us; speedup vs baseline: 1.8561x; 1.0288x over previous
//
#include <hip/hip_runtime.h>
#include <hip/hip_bf16.h>
#include <math.h>

#define NB 256
#define NL 256
#define NH 128
#define NK 8

typedef __attribute__((ext_vector_type(8))) short bf16x8;
typedef __attribute__((ext_vector_type(4))) short s16x4;
typedef __attribute__((ext_vector_type(4))) float f32x4;

static __device__ __forceinline__ short f2bf(float x) {
    __hip_bfloat16 b = __float2bfloat16(x);
    return *reinterpret_cast<short*>(&b);
}
static __device__ __forceinline__ float bf2f(short s) {
    union { unsigned int u; float f; } v;
    v.u = ((unsigned int)(unsigned short)s) << 16;
    return v.f;
}

#define MFMA __builtin_amdgcn_mfma_f32_16x16x32_bf16

// ---------------------------------------------------------------------------
// Setup: split W into bf16 hi/lo + transposed copies (global, L2/L3-hot).
// ---------------------------------------------------------------------------
__global__ __launch_bounds__(256) void setup_w_kernel(const float* __restrict__ W,
                                                      short* __restrict__ whi,
                                                      short* __restrict__ wlo,
                                                      short* __restrict__ wthi,
                                                      short* __restrict__ wtlo) {
    const int id = blockIdx.x * 256 + threadIdx.x;   // h*128 + j
    const int h = id >> 7, j = id & 127;
    const float w = W[id];
    const short hi = f2bf(w);
    const short lo = f2bf(w - bf2f(hi));
    whi[id] = hi;
    wlo[id] = lo;
    wthi[j * 128 + h] = hi;
    wtlo[j * 128 + h] = lo;
}

// ---------------------------------------------------------------------------
// Fused per-batch kernel: 256 blocks x 1024 threads (16 waves).
// Round-17 structure + (a) P3 W-fragments preloaded into registers (loop-
// invariant; 32 VGPRs), (b) mu phase deleted: P9 consumes m (mpk) directly,
// folding 1/||m|| into the post-MFMA scale; Gram self-normalizes from mpk.
// ---------------------------------------------------------------------------
__global__ __launch_bounds__(1024) void fused_kernel(const float* __restrict__ e,
                                                     const float* __restrict__ b_init,
                                                     const short* __restrict__ whi,
                                                     const short* __restrict__ wlo,
                                                     const short* __restrict__ wthi,
                                                     const short* __restrict__ wtlo,
                                                     float* __restrict__ out) {
    const int b = blockIdx.x;
    const int t = threadIdx.x;
    const int lane = t & 63, wv = t >> 6;
    const int l16 = lane & 15, grp = lane >> 4;

    __shared__ __align__(16) short eThi[128 * 264]; // 67584 B  e^T hi
    __shared__ __align__(16) short eTlo[128 * 264]; // 67584 B  e^T lo
    __shared__ __align__(16) short cax[16 * 264];   // 8448 B   raw exp rows 0-7 hi, 8-15 lo
    __shared__ __align__(16) short mpk[16 * 136];   // 4352 B   m_raw hi/lo
    __shared__ __align__(16) short cappk[16 * 136]; // 4352 B   cap (ksum-scaled) hi/lo
    __shared__ __align__(16) short gpk[16 * 136];   // 4352 B   g hi/lo
    __shared__ float enl[256];                      // 1024 B
    __shared__ float red32[128];                    // 512 B
    __shared__ __align__(16) float nrmp[64];        // 256 B
    __shared__ float ksf[8], svals[8], strv[8], Ps[28];

    const float* ebg = e + (size_t)b * (NL * NH);

    // ---- per-lane e row-fragments (P6/P9 A-operand) + row norms ----
    bf16x8 eah[4], eal[4];
    {
        const int row = wv * 16 + l16;
        float ss = 0.f;
#pragma unroll
        for (int ks = 0; ks < 4; ++ks) {
            const float4 f0 = *(const float4*)&ebg[row * 128 + ks * 32 + grp * 8];
            const float4 f1 = *(const float4*)&ebg[row * 128 + ks * 32 + grp * 8 + 4];
            const float fx[8] = {f0.x, f0.y, f0.z, f0.w, f1.x, f1.y, f1.z, f1.w};
            bf16x8 hv, lv;
#pragma unroll
            for (int j = 0; j < 8; ++j) {
                const short h = f2bf(fx[j]);
                hv[j] = h;
                lv[j] = f2bf(fx[j] - bf2f(h));
                ss += fx[j] * fx[j];
            }
            eah[ks] = hv;
            eal[ks] = lv;
        }
        ss += __shfl_xor(ss, 16);
        ss += __shfl_xor(ss, 32);
        if (grp == 0) enl[row] = sqrtf(ss) + 1e-8f;
    }

    // ---- P3's W fragments -> registers (loop-invariant; waves 0-7 only) ----
    bf16x8 wh3[4], wl3[4];
    if (wv < 8) {
#pragma unroll
        for (int ks = 0; ks < 4; ++ks) {
            const int bo = (wv * 16 + l16) * 128 + ks * 32 + grp * 8;
            wh3[ks] = *(const bf16x8*)&whi[bo];
            wl3[ks] = *(const bf16x8*)&wlo[bo];
        }
    }

    // ---- stage e^T (bf16 hi/lo): coalesced column-gather ----
#pragma unroll
    for (int i = 0; i < 4; ++i) {
        const int p = i * 1024 + t;
        const int h = p & 127, c = p >> 7;
        float le[8];
#pragma unroll
        for (int j = 0; j < 8; ++j) le[j] = ebg[(c * 8 + j) * 128 + h];
        bf16x8 hv, lv;
#pragma unroll
        for (int j = 0; j < 8; ++j) {
            const short s = f2bf(le[j]);
            hv[j] = s;
            lv[j] = f2bf(le[j] - bf2f(s));
        }
        *(bf16x8*)&eThi[h * 264 + c * 8] = hv;
        *(bf16x8*)&eTlo[h * 264 + c * 8] = lv;
    }

    // ---- logits in regs: lane l16<8 = capsule k, l = wv*16+grp*4+r ----
    float lr0 = 0.f, lr1 = 0.f, lr2 = 0.f, lr3 = 0.f;
    if (l16 < 8) {
        const float4 bi = *(const float4*)&b_init[(size_t)b * 2048 + l16 * 256 + wv * 16 + grp * 4];
        lr0 = bi.x; lr1 = bi.y; lr2 = bi.z; lr3 = bi.w;
    }

    // ---- hoisted iter-0 P1: raw exp (no norm, no max-sub; f32-safe) ----
    {
        const float e0 = expf(lr0), e1 = expf(lr1);
        const float e2 = expf(lr2), e3 = expf(lr3);
        float s4 = e0 + e1 + e2 + e3;
        s4 += __shfl_xor(s4, 16);
        s4 += __shfl_xor(s4, 32);
        if (l16 < 8 && grp == 0) red32[wv * 8 + l16] = s4;
        if (l16 < 8) {
            const int lb = wv * 16 + grp * 4;
            const float cv[4] = {e0, e1, e2, e3};
            s16x4 his, los;
#pragma unroll
            for (int j = 0; j < 4; ++j) {
                const short h = f2bf(cv[j]);
                his[j] = h;
                los[j] = f2bf(cv[j] - bf2f(h));
            }
            *(s16x4*)&cax[l16 * 264 + lb] = his;
            *(s16x4*)&cax[(l16 + 8) * 264 + lb] = los;
        }
    }
    __syncthreads();   // B0: staging + iter-0 exp ready

    for (int iter = 0; iter < 3; ++iter) {
        // ===== P2: m_raw = exp @ e  (A=[exp_hi;exp_lo], B=eT hi/lo, waves 0-7) =====
        if (wv < 8) {
            const int n0 = wv * 16;
            f32x4 ac0 = (f32x4){0.f, 0.f, 0.f, 0.f};
            f32x4 ac1 = (f32x4){0.f, 0.f, 0.f, 0.f};
#pragma unroll
            for (int ks = 0; ks < 4; ++ks) {
                const bf16x8 af = *(const bf16x8*)&cax[l16 * 264 + ks * 32 + grp * 8];
                const bf16x8 bh = *(const bf16x8*)&eThi[(n0 + l16) * 264 + ks * 32 + grp * 8];
                const bf16x8 bl = *(const bf16x8*)&eTlo[(n0 + l16) * 264 + ks * 32 + grp * 8];
                ac0 = MFMA(af, bh, ac0, 0, 0, 0);
                ac0 = MFMA(af, bl, ac0, 0, 0, 0);
            }
#pragma unroll
            for (int ks = 4; ks < 8; ++ks) {
                const bf16x8 af = *(const bf16x8*)&cax[l16 * 264 + ks * 32 + grp * 8];
                const bf16x8 bh = *(const bf16x8*)&eThi[(n0 + l16) * 264 + ks * 32 + grp * 8];
                const bf16x8 bl = *(const bf16x8*)&eTlo[(n0 + l16) * 264 + ks * 32 + grp * 8];
                ac1 = MFMA(af, bh, ac1, 0, 0, 0);
                ac1 = MFMA(af, bl, ac1, 0, 0, 0);
            }
            const f32x4 acc = ac0 + ac1;
            f32x4 ms;
#pragma unroll
            for (int r = 0; r < 4; ++r) ms[r] = acc[r] + __shfl_xor(acc[r], 32);
            if (grp < 2) {
#pragma unroll
                for (int r = 0; r < 4; ++r) {
                    const int k = grp * 4 + r, h = n0 + l16;
                    const short hv = f2bf(ms[r]);
                    mpk[k * 136 + h] = hv;
                    mpk[(k + 8) * 136 + h] = f2bf(ms[r] - bf2f(hv));
                }
            }
        }
        __syncthreads();   // B2

        // ===== P3: cap = (m_raw @ W^T) * (1/ksum)  + norm partials =====
        if (wv < 8) {
            float inv = 0.f;
            if (l16 < 8) {
                float kss = 0.f;
#pragma unroll
                for (int w = 0; w < 16; ++w) kss += red32[w * 8 + l16];
                inv = 1.0f / kss;
            }
            const int n0 = wv * 16;
            f32x4 acc = (f32x4){0.f, 0.f, 0.f, 0.f};
#pragma unroll
            for (int ks = 0; ks < 4; ++ks) {
                const bf16x8 af = *(const bf16x8*)&mpk[l16 * 136 + ks * 32 + grp * 8];
                acc = MFMA(af, wh3[ks], acc, 0, 0, 0);
                acc = MFMA(af, wl3[ks], acc, 0, 0, 0);
            }
            f32x4 cs;
            float pn[4];
#pragma unroll
            for (int r = 0; r < 4; ++r) {
                cs[r] = acc[r] + __shfl_xor(acc[r], 32);
                cs[r] *= __shfl(inv, grp * 4 + r);
                float p2 = cs[r] * cs[r];
                p2 += __shfl_xor(p2, 1);
                p2 += __shfl_xor(p2, 2);
                p2 += __shfl_xor(p2, 4);
                p2 += __shfl_xor(p2, 8);
                pn[r] = p2;
            }
            if (l16 == 0 && grp < 2) {
                float4 pv;
                pv.x = pn[0]; pv.y = pn[1]; pv.z = pn[2]; pv.w = pn[3];
                *(float4*)&nrmp[wv * 8 + grp * 4] = pv;
            }
            if (iter < 2 && grp < 2) {
#pragma unroll
                for (int r = 0; r < 4; ++r) {
                    const int k2 = grp * 4 + r, h = n0 + l16;
                    const short hv = f2bf(cs[r]);
                    cappk[k2 * 136 + h] = hv;
                    cappk[(k2 + 8) * 136 + h] = f2bf(cs[r] - bf2f(hv));
                }
            }
            if (iter == 2 && wv == 0 && grp == 0 && l16 < 8) ksf[l16] = inv;
        }
        __syncthreads();   // B3

        if (iter < 2) {
            // ===== P5: g = (cap @ W) * squash_scale(k) =====
            if (wv < 8) {
                float sc = 0.f;
                if (l16 < 8) {
                    float n = 0.f;
#pragma unroll
                    for (int w = 0; w < 8; ++w) n += nrmp[w * 8 + l16];
                    sc = n / (1.0f + n) / sqrtf(n + 1e-9f);
                }
                const int n0 = wv * 16;
                f32x4 acc = (f32x4){0.f, 0.f, 0.f, 0.f};
#pragma unroll
                for (int ks = 0; ks < 4; ++ks) {
                    const bf16x8 af = *(const bf16x8*)&cappk[l16 * 136 + ks * 32 + grp * 8];
                    const int bo = (n0 + l16) * 128 + ks * 32 + grp * 8;
                    acc = MFMA(af, *(const bf16x8*)&wthi[bo], acc, 0, 0, 0);
                    acc = MFMA(af, *(const bf16x8*)&wtlo[bo], acc, 0, 0, 0);
                }
                f32x4 gs;
#pragma unroll
                for (int r = 0; r < 4; ++r) {
                    gs[r] = acc[r] + __shfl_xor(acc[r], 32);
                    gs[r] *= __shfl(sc, grp * 4 + r);
                }
                if (grp < 2) {
#pragma unroll
                    for (int r = 0; r < 4; ++r) {
                        const int k2 = grp * 4 + r, h = n0 + l16;
                        const short hv = f2bf(gs[r]);
                        gpk[k2 * 136 + h] = hv;
                        gpk[(k2 + 8) * 136 + h] = f2bf(gs[r] - bf2f(hv));
                    }
                }
            }
            __syncthreads();   // B4

            // ===== P6: logits += e . g  (A=e regs, C=logits)  + fused P1 =====
            {
                f32x4 acc;
                acc[0] = (l16 < 8) ? lr0 : 0.f;
                acc[1] = (l16 < 8) ? lr1 : 0.f;
                acc[2] = (l16 < 8) ? lr2 : 0.f;
                acc[3] = (l16 < 8) ? lr3 : 0.f;
#pragma unroll
                for (int ks = 0; ks < 4; ++ks) {
                    const bf16x8 bf = *(const bf16x8*)&gpk[l16 * 136 + ks * 32 + grp * 8];
                    acc = MFMA(eah[ks], bf, acc, 0, 0, 0);
                    acc = MFMA(eal[ks], bf, acc, 0, 0, 0);
                }
                lr0 = acc[0] + __shfl_xor(acc[0], 8);
                lr1 = acc[1] + __shfl_xor(acc[1], 8);
                lr2 = acc[2] + __shfl_xor(acc[2], 8);
                lr3 = acc[3] + __shfl_xor(acc[3], 8);
                // fused P1 for iter+1 (register work; barrier below orders writes)
                const float e0 = expf(lr0), e1 = expf(lr1);
                const float e2 = expf(lr2), e3 = expf(lr3);
                float s4 = e0 + e1 + e2 + e3;
                s4 += __shfl_xor(s4, 16);
                s4 += __shfl_xor(s4, 32);
                if (l16 < 8 && grp == 0) red32[wv * 8 + l16] = s4;
                if (l16 < 8) {
                    const int lb = wv * 16 + grp * 4;
                    const float cv[4] = {e0, e1, e2, e3};
                    s16x4 his, los;
#pragma unroll
                    for (int j = 0; j < 4; ++j) {
                        const short h = f2bf(cv[j]);
                        his[j] = h;
                        los[j] = f2bf(cv[j] - bf2f(h));
                    }
                    *(s16x4*)&cax[l16 * 264 + lb] = his;
                    *(s16x4*)&cax[(l16 + 8) * 264 + lb] = los;
                }
            }
            __syncthreads();   // B5
        }
    }

    // ===== tail (after iter-2 B3): strength ∥ P9 from m directly ∥ Gram =====
    if (wv == 8 && lane < 8) {
        float n = 0.f;
#pragma unroll
        for (int w = 0; w < 8; ++w) n += nrmp[w * 8 + lane];
        strv[lane] = n / (1.0f + n) * sqrtf(n) / sqrtf(n + 1e-9f);
    }

    // P9: dot = e . m (MFMA, B = mpk rows directly), normalize post-MFMA.
    {
        f32x4 acc = (f32x4){0.f, 0.f, 0.f, 0.f};
        float phi = 0.f;
#pragma unroll
        for (int ks = 0; ks < 4; ++ks) {
            const int off = ks * 32 + grp * 8;
            const bf16x8 bh = *(const bf16x8*)&mpk[(l16 & 7) * 136 + off];
            const bf16x8 bl = *(const bf16x8*)&mpk[((l16 & 7) + 8) * 136 + off];
#pragma unroll
            for (int j = 0; j < 8; ++j) {
                const float mv = bf2f(bh[j]) + bf2f(bl[j]);
                phi += mv * mv;
            }
            const bf16x8 bf = (l16 < 8) ? bh : bl;
            acc = MFMA(eah[ks], bf, acc, 0, 0, 0);
            acc = MFMA(eal[ks], bf, acc, 0, 0, 0);
        }
        phi += __shfl_xor(phi, 16);
        phi += __shfl_xor(phi, 32);   // ||m_k||^2 over all 128 h
        float sv = 0.f;
        if (l16 < 8) {
            const float kinv = ksf[l16];
            const float invnv = 1.0f / (sqrtf(phi) + 1e-8f);
#pragma unroll
            for (int r = 0; r < 4; ++r) {
                const float d = acc[r] + __shfl_xor(acc[r], 8);   // e . (m_hi+m_lo)
                const int l = wv * 16 + grp * 4 + r;
                const float cv = (bf2f(cax[l16 * 264 + l]) + bf2f(cax[(l16 + 8) * 264 + l])) * kinv;
                sv += d * cv * invnv / enl[l];
            }
        }
        sv += __shfl_xor(sv, 16);
        sv += __shfl_xor(sv, 32);
        if (l16 < 8 && grp == 0) red32[wv * 8 + l16] = sv;
    }

    // Gram pairs from m (self-normalizing cosines)
#pragma unroll
    for (int pp = 0; pp < 2; ++pp) {
        const int p = wv + pp * 16;
        if (p < 28) {
            int i = 0, rem = p;
            while (rem >= 7 - i) { rem -= 7 - i; ++i; }
            const int j = i + 1 + rem;
            const float mi0 = bf2f(mpk[i * 136 + lane]) + bf2f(mpk[(i + 8) * 136 + lane]);
            const float mi1 = bf2f(mpk[i * 136 + 64 + lane]) + bf2f(mpk[(i + 8) * 136 + 64 + lane]);
            const float mj0 = bf2f(mpk[j * 136 + lane]) + bf2f(mpk[(j + 8) * 136 + lane]);
            const float mj1 = bf2f(mpk[j * 136 + 64 + lane]) + bf2f(mpk[(j + 8) * 136 + 64 + lane]);
            float vij = mi0 * mj0 + mi1 * mj1;
            float vii = mi0 * mi0 + mi1 * mi1;
            float vjj = mj0 * mj0 + mj1 * mj1;
#pragma unroll
            for (int o = 32; o; o >>= 1) {
                vij += __shfl_xor(vij, o);
                vii += __shfl_xor(vii, o);
                vjj += __shfl_xor(vjj, o);
            }
            if (lane == 0)
                Ps[p] = vij / ((sqrtf(vii) + 1e-8f) * (sqrtf(vjj) + 1e-8f));
        }
    }
    __syncthreads();   // B7
    if (t < 8) {
        float s = 0.f;
#pragma unroll
        for (int w = 0; w < 16; ++w) s += red32[w * 8 + t];
        svals[t] = s;
    }
    __syncthreads();   // B8

    // ===== serial scoring =====
    if (t == 0) {
        int idx[8];
        for (int i = 0; i < 8; ++i) idx[i] = i;
        for (int a = 1; a < 8; ++a) {
            const int key = idx[a];
            const float kv = strv[key];
            int bb = a - 1;
            while (bb >= 0 && strv[idx[bb]] < kv) { idx[bb + 1] = idx[bb]; --bb; }
            idx[bb + 1] = key;
        }
        float best = -1e30f;
        int bestk = 2;
        float cons_sum = 0.f, pair_sum = 0.f;
        for (int kk = 1; kk <= 8; ++kk) {
            const int ni = idx[kk - 1];
            cons_sum += svals[ni];
            for (int a = 0; a < kk - 1; ++a) {
                const int ia = idx[a];
                const int lo = ia < ni ? ia : ni;
                const int hi2 = ia < ni ? ni : ia;
                const int off0 = lo * 7 - lo * (lo - 1) / 2;
                pair_sum += Ps[off0 + hi2 - lo - 1];
            }
            if (kk >= 2) {
                const float cons = cons_sum / (kk * 256.0f);
                const float divv = 1.0f - (2.0f / (kk * (kk - 1))) * pair_sum;
                const float score = 0.5f * cons + 0.5f * divv;
                out[256 + b * 7 + (kk - 2)] = score;
                if (score > best) { best = score; bestk = kk; }
            }
        }
        out[b] = (float)bestk;
    }
}

// ---------------------------------------------------------------------------
extern "C" void kernel_launch(void* const* d_in, const int* in_sizes, int n_in,
                              void* d_out, int out_size, void* d_ws, size_t ws_size,
                              hipStream_t stream) {
    const float* e = (const float*)d_in[0];
    const float* W = (const float*)d_in[1];
    const float* b_init = (const float*)d_in[2];
    float* out = (float*)d_out;

    short* whi = (short*)d_ws;
    short* wlo = whi + 16384;
    short* wthi = wlo + 16384;
    short* wtlo = wthi + 16384;

    hipLaunchKernelGGL(setup_w_kernel, dim3(64), dim3(256), 0, stream, W, whi, wlo, wthi, wtlo);
    hipLaunchKernelGGL(fused_kernel, dim3(NB), dim3(1024), 0, stream,
                       e, b_init, whi, wlo, wthi, wtlo, out);
}